// Round 14
// baseline (47.466 us; speedup 1.0000x reference)
//
#include <hip/hip_runtime.h>
#include <math.h>

#define C_CH 256
#define KTOP 26
#define HWSZ 3136            // 56*56
#define NPIX 100352          // 32*3136
#define CHW  (C_CH * HWSZ)
#define PPB  32              // pixels per tile
#define TPI  98              // tiles per image (3136/32)
#define CPT  32              // channels per lane-half

typedef float f32x4 __attribute__((ext_vector_type(4)));

// Raw barrier: LDS-visible, does NOT drain vmcnt (keeps staging in flight).
#define BAR_LDS() do { \
    asm volatile("s_waitcnt lgkmcnt(0)" ::: "memory"); \
    __builtin_amdgcn_sched_barrier(0); \
    __builtin_amdgcn_s_barrier(); \
} while (0)

// Wave-local wait for this wave's outstanding VMEM (stage loads + old stores).
#define WAIT_VM() do { \
    asm volatile("s_waitcnt vmcnt(0)" ::: "memory"); \
    __builtin_amdgcn_sched_barrier(0); \
} while (0)

__device__ __forceinline__ void ce_desc(float& a, float& b) {
    float mx = fmaxf(a, b); float mn = fminf(a, b); a = mx; b = mn;
}
__device__ __forceinline__ void ce_asc(float& a, float& b) {
    float mn = fminf(a, b); float mx = fmaxf(a, b); a = mn; b = mx;
}

__device__ __forceinline__ void sort32_desc(float* v) {
#pragma unroll
    for (int k = 2; k <= 32; k <<= 1) {
#pragma unroll
        for (int j = k >> 1; j > 0; j >>= 1) {
#pragma unroll
            for (int i = 0; i < 32; ++i) {
                int l = i ^ j;
                if (l > i) {
                    if ((i & k) == 0) ce_desc(v[i], v[l]);
                    else              ce_asc(v[i], v[l]);
                }
            }
        }
    }
}

__device__ __forceinline__ void clean32_desc(float* v) {
#pragma unroll
    for (int j = 16; j > 0; j >>= 1) {
#pragma unroll
        for (int i = 0; i < 32; ++i) {
            int l = i ^ j;
            if (l > i) ce_desc(v[i], v[l]);
        }
    }
}

// a (desc-26) + LDS desc-26 -> a = sorted top-26 of union. (verified R2-R12)
__device__ __forceinline__ void merge26(float* a, const float* __restrict__ src) {
    float h[32];
#pragma unroll
    for (int i = 0; i < 32; ++i) {
        float u = (i < KTOP)      ? a[i]        : -INFINITY;
        float w = (31 - i < KTOP) ? src[31 - i] : -INFINITY;
        h[i] = fmaxf(u, w);
    }
    clean32_desc(h);
#pragma unroll
    for (int j = 0; j < KTOP; ++j) a[j] = h[j];
}

__global__ __launch_bounds__(256, 2) void kwinners_kernel(
    const float* __restrict__ x, const float* __restrict__ duty,
    const float* __restrict__ bsp, float* __restrict__ out)
{
    __shared__ float s[C_CH];
    __shared__ float tileA[C_CH][PPB];           // 32 KB
    __shared__ float tileB[C_CH][PPB];           // 32 KB
    __shared__ float pub[2][PPB][26];            // 6.5 KB, thr in pub[0][pl][0]
    // Total LDS = 1024 + 65536 + 6656 = 73216 -> 2 blocks/CU.

    const int t  = threadIdx.x;
    const int w  = t >> 6;                  // wave id (0..3)
    const int l  = t & 63;                  // lane
    const int pl = l & 31;                  // pixel within tile
    const int hf = l >> 5;                  // lane half

    const int tid0 = blockIdx.x * 2;        // two consecutive tiles per block
    const int b0   = tid0 / TPI;
    const int h0   = (tid0 - b0 * TPI) * PPB;
    const int tid1 = tid0 + 1;              // tid0 even -> same-image pair
    const int b1   = tid1 / TPI;
    const int h1   = (tid1 - b1 * TPI) * PPB;

    const float* xb0 = x + (size_t)b0 * CHW + h0;
    const float* xb1 = x + (size_t)b1 * CHW + h1;
    float* ob0 = out + (size_t)b0 * CHW + h0;
    float* ob1 = out + (size_t)b1 * CHW + h1;

    // Wave-local stage: wave w loads ITS rows [64w,64w+64) (consumed only by
    // wave w pre-pub). Per instr: 64 lanes x 16B = 8 rows x 128B, LDS dest
    // linear (base + lane*16, HW rule). Lane l -> row (l>>3), quad l&7.
    auto stage = [&](float (*tile)[PPB], const float* xb) {
        const int row0 = w * 64;
        const float* gp = xb + (size_t)(row0 + (l >> 3)) * HWSZ + (l & 7) * 4;
#pragma unroll
        for (int it = 0; it < 8; ++it) {
            __builtin_amdgcn_global_load_lds(
                (const __attribute__((address_space(1))) void*)(gp + (size_t)it * 8 * HWSZ),
                (__attribute__((address_space(3))) void*)&tile[row0 + it * 8][0],
                16, 0, 0);
        }
    };

    // Process one tile (R12's verified structure, raw-barrier edition).
    // If xn != nullptr, issue stage(next tile) right after the boost-read so
    // it flies under sort/merge/write (raw barriers don't drain vmcnt).
    auto process = [&](float (*tile)[PPB], const float* xn, float (*tn)[PPB],
                       float* ob) {
        // Protects pub reuse across tiles: every wave arriving here has
        // finished its previous write phase (thr reads included).
        BAR_LDS();

        const int c0 = w * 64 + hf * 32;
        const float* sc = s + c0;

        float v[CPT];
#pragma unroll
        for (int i = 0; i < CPT; ++i) v[i] = tile[c0 + i][pl] * sc[i];

        if (xn) stage(tn, xn);              // prefetch next tile now

        sort32_desc(v);

        // L1 (intra-wave): merge with partner half via shfl. (verified)
        float a[KTOP];
        {
            float h[32];
#pragma unroll
            for (int i = 0; i < 32; ++i) {
                float u  = (i < KTOP)      ? v[i] : -INFINITY;
                float pw = (31 - i < KTOP) ? __shfl_xor(v[31 - i], 32) : -INFINITY;
                h[i] = fmaxf(u, pw);
            }
            clean32_desc(h);
#pragma unroll
            for (int j = 0; j < KTOP; ++j) a[j] = h[j];
        }

        // Publish: wave1 -> pub[0], wave3 -> pub[1]
        if ((w & 1) && l < 32) {
            float* dst = pub[w >> 1][pl];
#pragma unroll
            for (int j = 0; j < KTOP; ++j) dst[j] = a[j];
        }
        BAR_LDS();

        // L2: wave0 <- pub[0], wave2 <- pub[1]; wave2 republishes
        if (w == 0) {
            merge26(a, pub[0][pl]);
        } else if (w == 2) {
            merge26(a, pub[1][pl]);
            if (l < 32) {
                float* dst = pub[1][pl];
#pragma unroll
                for (int j = 0; j < KTOP; ++j) dst[j] = a[j];
            }
        }
        BAR_LDS();

        // L3 (wave 0): rank-25 of merge(a, pub[1]) via cascade. (verified)
        if (w == 0) {
            const float* src = pub[1][pl];
            float h[32];
#pragma unroll
            for (int i = 0; i < 32; ++i) {
                float u  = (i < KTOP)      ? a[i]        : -INFINITY;
                float wv = (31 - i < KTOP) ? src[31 - i] : -INFINITY;
                h[i] = fmaxf(u, wv);
            }
            float l16[16];
#pragma unroll
            for (int i = 0; i < 16; ++i) l16[i] = fminf(h[i], h[i + 16]);
            float l8[8];
#pragma unroll
            for (int i = 0; i < 8; ++i)  l8[i]  = fminf(l16[i], l16[i + 8]);
            float h4[4];
#pragma unroll
            for (int i = 0; i < 4; ++i)  h4[i]  = fmaxf(l8[i], l8[i + 4]);
            float h2[2];
#pragma unroll
            for (int i = 0; i < 2; ++i)  h2[i]  = fmaxf(h4[i], h4[i + 2]);
            if (l < 32) pub[0][pl][0] = fminf(h2[0], h2[1]);
        }
        BAR_LDS();

        // Vectorized write: lane -> (row8 = l>>3, px-group = l&7);
        // ds_read_b128 + NT dwordx4 store, 8 iters over this wave's 64 rows.
        {
            const int pg   = l & 7;
            const int r8   = l >> 3;
            const int row0 = w * 64;
            const float t0 = pub[0][pg * 4 + 0][0];
            const float t1 = pub[0][pg * 4 + 1][0];
            const float t2 = pub[0][pg * 4 + 2][0];
            const float t3 = pub[0][pg * 4 + 3][0];

            float* opb = ob + (size_t)(row0 + r8) * HWSZ + pg * 4;
#pragma unroll
            for (int it = 0; it < 8; ++it) {
                const int r = row0 + it * 8 + r8;
                const f32x4 xv = *reinterpret_cast<const f32x4*>(&tile[r][pg * 4]);
                const float scv = s[r];
                f32x4 res;
                res.x = (xv.x * scv >= t0) ? xv.x : 0.0f;
                res.y = (xv.y * scv >= t1) ? xv.y : 0.0f;
                res.z = (xv.z * scv >= t2) ? xv.z : 0.0f;
                res.w = (xv.w * scv >= t3) ? xv.w : 0.0f;
                __builtin_nontemporal_store(
                    res, reinterpret_cast<f32x4*>(&opb[(size_t)(it * 8) * HWSZ]));
            }
        }
    };

    // ---- Prologue: stage tile0; exp table while loads fly ----
    stage(tileA, xb0);
    {
        // scale = exp(-bs*duty[c]); fp32 mul, exp in double rounded to fp32
        // -> correctly-rounded. Wave-local consumption. (absmax=0, R1-R13)
        float bs = bsp[0];
        float m = -(bs * duty[t]);
        s[t] = (float)exp((double)m);
    }

    // ---- Tile 0 (stages tile1 under its compute) ----
    WAIT_VM();                  // tile0 staged (wave-local)
    process(tileA, xb1, tileB, ob0);

    // ---- Tile 1 ----
    WAIT_VM();                  // tile1 staged (landed during tile0 work)
    process(tileB, nullptr, nullptr, ob1);
}

extern "C" void kernel_launch(void* const* d_in, const int* in_sizes, int n_in,
                              void* d_out, int out_size, void* d_ws, size_t ws_size,
                              hipStream_t stream) {
    const float* x    = (const float*)d_in[0];
    const float* duty = (const float*)d_in[1];
    // d_in[2] = k (int, ==26 hardcoded), d_in[3] = boost_strength (float)
    const float* bs   = (const float*)d_in[3];
    float* out = (float*)d_out;

    hipLaunchKernelGGL(kwinners_kernel, dim3(NPIX / (PPB * 2)), dim3(256), 0,
                       stream, x, duty, bs, out);
}

// Round 15
// 37.738 us; speedup vs baseline: 1.2578x; 1.2578x over previous
//
#include <hip/hip_runtime.h>
#include <math.h>

#define C_CH 256
#define KTOP 26
#define HWSZ 3136            // 56*56
#define NPIX 100352          // 32*3136
#define CHW  (C_CH * HWSZ)
#define PIX_PER_BLK 32
#define BLKS_PER_IMG 98      // 3136 / 32
#define CPT 32               // channels per lane-half (C_CH / 8)

typedef float f32x4 __attribute__((ext_vector_type(4)));

__device__ __forceinline__ void ce_desc(float& a, float& b) {
    float mx = fmaxf(a, b); float mn = fminf(a, b); a = mx; b = mn;
}
__device__ __forceinline__ void ce_asc(float& a, float& b) {
    float mn = fminf(a, b); float mx = fmaxf(a, b); a = mn; b = mx;
}

// Full bitonic sort of 32 values -> descending. 240 CE, static indices.
__device__ __forceinline__ void sort32_desc(float* v) {
#pragma unroll
    for (int k = 2; k <= 32; k <<= 1) {
#pragma unroll
        for (int j = k >> 1; j > 0; j >>= 1) {
#pragma unroll
            for (int i = 0; i < 32; ++i) {
                int l = i ^ j;
                if (l > i) {
                    if ((i & k) == 0) ce_desc(v[i], v[l]);
                    else              ce_asc(v[i], v[l]);
                }
            }
        }
    }
}

// Clean an already-bitonic 32 sequence -> descending. 80 CE.
__device__ __forceinline__ void clean32_desc(float* v) {
#pragma unroll
    for (int j = 16; j > 0; j >>= 1) {
#pragma unroll
        for (int i = 0; i < 32; ++i) {
            int l = i ^ j;
            if (l > i) ce_desc(v[i], v[l]);
        }
    }
}

// Merge own desc-26 (a[0..25]) with LDS desc-26 list -> a = sorted top-26 of
// union. [a pad32 desc | rev(src) pad32 asc] is bitonic-64; max-half keeps
// ranks 0..31 (bitonic), clean -> sorted desc. (verified R2-R14)
__device__ __forceinline__ void merge26(float* a, const float* __restrict__ src) {
    float h[32];
#pragma unroll
    for (int i = 0; i < 32; ++i) {
        float u = (i < KTOP)      ? a[i]        : -INFINITY;
        float w = (31 - i < KTOP) ? src[31 - i] : -INFINITY;
        h[i] = fmaxf(u, w);
    }
    clean32_desc(h);
#pragma unroll
    for (int j = 0; j < KTOP; ++j) a[j] = h[j];
}

__global__ __launch_bounds__(256)
__attribute__((amdgpu_waves_per_eu(4)))        // hard VGPR budget: 512/4 = 128
void kwinners_kernel(
    const float* __restrict__ x, const float* __restrict__ duty,
    const float* __restrict__ bsp, float* __restrict__ out)
{
    __shared__ float s[C_CH];
    __shared__ float tile[C_CH][PIX_PER_BLK];    // 32 KB x-tile
    __shared__ float pub[2][PIX_PER_BLK][26];    // stride 26: 2-way (free)
    // threshold aliased into pub[0][pl][0] after pub[0] is dead (level-3).
    // Total LDS = 32768 + 1024 + 6656 = 40448 -> 4 blocks/CU at 4 waves/EU.

    const int t   = threadIdx.x;
    const int w   = t >> 6;                 // wave id (0..3)
    const int l   = t & 63;                 // lane
    const int pl  = l & 31;                 // pixel within block
    const int hf  = l >> 5;                 // lane half
    const int blk = blockIdx.x;
    const int b   = blk / BLKS_PER_IMG;
    const int hw0 = (blk - b * BLKS_PER_IMG) * PIX_PER_BLK;

    // ---- Stage this wave's 64 channel-rows into LDS (async, no VGPR dest).
    // Per instr: 64 lanes x 16B = 8 rows of 32px; dest = uniform base + lane*16
    // (HW rule). Lane l -> row (l>>3), pixels (l&7)*4 .. +3.
    {
        const int row0 = w * 64;
        const float* gp = x + (size_t)b * CHW + (size_t)(row0 + (l >> 3)) * HWSZ
                            + hw0 + (l & 7) * 4;
#pragma unroll
        for (int it = 0; it < 8; ++it) {
            __builtin_amdgcn_global_load_lds(
                (const __attribute__((address_space(1))) void*)(gp + (size_t)it * 8 * HWSZ),
                (__attribute__((address_space(3))) void*)&tile[row0 + it * 8][0],
                16, 0, 0);
        }
    }

    // exp table while loads fly. Wave-local consumption pre-pub (wave w reads
    // only s[64w..64w+64) / tile rows [64w,64w+64)). scale = exp(-bs*duty[c]);
    // fp32 mul, exp in double rounded to fp32 -> correctly-rounded.
    // (absmax=0, R1-R14)
    {
        float bs = bsp[0];
        float m = -(bs * duty[t]);
        s[t] = (float)exp((double)m);
    }

    // Wave-local drain of this wave's global_load_lds (replaces block-wide
    // __syncthreads): each wave proceeds as soon as ITS loads land. (R12)
    asm volatile("s_waitcnt vmcnt(0)" ::: "memory");
    __builtin_amdgcn_sched_barrier(0);

    const int c0 = w * 64 + hf * 32;        // this lane-half's channel group

    // ---- Boost+sort+L1 in a tight scope so v[] dies at L1's end ----
    float a[KTOP];
    {
        const float* sc = s + c0;
        float v[CPT];
#pragma unroll
        for (int i = 0; i < CPT; ++i) v[i] = tile[c0 + i][pl] * sc[i];

        sort32_desc(v);

        // L1 (intra-wave): merge with partner half via shfl. (verified)
        float h[32];
#pragma unroll
        for (int i = 0; i < 32; ++i) {
            float u  = (i < KTOP)      ? v[i] : -INFINITY;
            float pw = (31 - i < KTOP) ? __shfl_xor(v[31 - i], 32) : -INFINITY;
            h[i] = fmaxf(u, pw);
        }
        clean32_desc(h);
#pragma unroll
        for (int j = 0; j < KTOP; ++j) a[j] = h[j];
    }
    // a = sorted top-26 of channels [64w, 64w+64), identical in both halves.

    // ---- Publish: wave1 -> pub[0], wave3 -> pub[1] ----
    if ((w & 1) && l < 32) {
        float* dst = pub[w >> 1][pl];
#pragma unroll
        for (int j = 0; j < KTOP; ++j) dst[j] = a[j];
    }
    __syncthreads();

    // ---- Level 2: wave0 <- pub[0], wave2 <- pub[1]; wave2 republishes ----
    if (w == 0) {
        merge26(a, pub[0][pl]);             // top-26 of ch 0..127
    } else if (w == 2) {
        merge26(a, pub[1][pl]);             // top-26 of ch 128..255
        if (l < 32) {
            float* dst = pub[1][pl];        // own source, safe to overwrite
#pragma unroll
            for (int j = 0; j < KTOP; ++j) dst[j] = a[j];
        }
    }
    __syncthreads();

    // ---- Level 3 (wave 0): rank-25 of merge(a, pub[1]) via cascade ----
    if (w == 0) {
        const float* src = pub[1][pl];
        float h[32];
#pragma unroll
        for (int i = 0; i < 32; ++i) {
            float u  = (i < KTOP)      ? a[i]        : -INFINITY;
            float wv = (31 - i < KTOP) ? src[31 - i] : -INFINITY;
            h[i] = fmaxf(u, wv);                      // ranks 0..31, r=25
        }
        float l16[16];
#pragma unroll
        for (int i = 0; i < 16; ++i) l16[i] = fminf(h[i], h[i + 16]);    // r=9
        float l8[8];
#pragma unroll
        for (int i = 0; i < 8; ++i)  l8[i]  = fminf(l16[i], l16[i + 8]); // r=1
        float h4[4];
#pragma unroll
        for (int i = 0; i < 4; ++i)  h4[i]  = fmaxf(l8[i], l8[i + 4]);   // r=1
        float h2[2];
#pragma unroll
        for (int i = 0; i < 2; ++i)  h2[i]  = fmaxf(h4[i], h4[i + 2]);   // r=1
        if (l < 32) pub[0][pl][0] = fminf(h2[0], h2[1]);   // thr (pub[0] dead)
    }
    __syncthreads();

    // ---- Vectorized write: lane -> (row8 = l>>3, px-group = l&7).
    // Per iter: ds_read_b128 (4 px of one row) + broadcast s[row] + 4 selects
    // + one NT dwordx4 store. 8 iters cover this wave's 64 rows x 32 px.
    {
        const int pg   = l & 7;             // pixel group (4 px)
        const int r8   = l >> 3;            // row within each 8-row step
        const int row0 = w * 64;
        const float t0 = pub[0][pg * 4 + 0][0];
        const float t1 = pub[0][pg * 4 + 1][0];
        const float t2 = pub[0][pg * 4 + 2][0];
        const float t3 = pub[0][pg * 4 + 3][0];

        float* opb = out + (size_t)b * CHW + (size_t)(row0 + r8) * HWSZ
                         + hw0 + pg * 4;
#pragma unroll
        for (int it = 0; it < 8; ++it) {
            const int r = row0 + it * 8 + r8;
            const f32x4 xv = *reinterpret_cast<const f32x4*>(&tile[r][pg * 4]);
            const float scv = s[r];
            f32x4 res;
            res.x = (xv.x * scv >= t0) ? xv.x : 0.0f;
            res.y = (xv.y * scv >= t1) ? xv.y : 0.0f;
            res.z = (xv.z * scv >= t2) ? xv.z : 0.0f;
            res.w = (xv.w * scv >= t3) ? xv.w : 0.0f;
            __builtin_nontemporal_store(
                res, reinterpret_cast<f32x4*>(&opb[(size_t)(it * 8) * HWSZ]));
        }
    }
}

extern "C" void kernel_launch(void* const* d_in, const int* in_sizes, int n_in,
                              void* d_out, int out_size, void* d_ws, size_t ws_size,
                              hipStream_t stream) {
    const float* x    = (const float*)d_in[0];
    const float* duty = (const float*)d_in[1];
    // d_in[2] = k (int, ==26 hardcoded), d_in[3] = boost_strength (float)
    const float* bs   = (const float*)d_in[3];
    float* out = (float*)d_out;

    hipLaunchKernelGGL(kwinners_kernel, dim3(NPIX / PIX_PER_BLK), dim3(256), 0,
                       stream, x, duty, bs, out);
}